// Round 11
// baseline (807.076 us; speedup 1.0000x reference)
//
#include <hip/hip_runtime.h>
#include <cstdint>
#include <cstddef>

// ---------------------------------------------------------------------------
// EncodeProcessDecode (MeshGraphNets-style GNN) on gfx950.
// N=20000 nodes, E=100000 edges, L=128, S=6 steps.
// Round 11 = r10 + LDS residual stash: layer-1 already reads the residual
// target rows (edge_lat for MODE 2, node_lat for MODE 3) as fp32; tee them
// into a 16.9KB LDS stash (stride 132, 2-way alias = free) and make the
// epilogue a pure store (old+y) -> kills 32 scattered RMW loads/wave and
// ~25MB of HBM re-reads per edge step. Bit-identical numerics.
// Kept from r10: single-wave blocks (64thr/32rows), phase-batched gathers,
// RT=2 (r9: RT=1 regressed), frag-major weights (r7), agg kernel (r8).
// ---------------------------------------------------------------------------

#define N_NODES 20000
#define N_EDGES 100000
#define LDIM    128
#define NSTEPS  6

typedef float  f32x4  __attribute__((ext_vector_type(4)));
typedef __bf16 bf16x8 __attribute__((ext_vector_type(8)));
typedef __bf16 bf16x2 __attribute__((ext_vector_type(2)));

// load 8 consecutive fp32, round to bf16x8 (one MFMA A-frag chunk)
__device__ __forceinline__ bf16x8 cvt8(const float* p) {
  float4 u = *(const float4*)p;
  float4 v = *(const float4*)(p + 4);
  bf16x8 o;
  o[0] = (__bf16)u.x; o[1] = (__bf16)u.y; o[2] = (__bf16)u.z; o[3] = (__bf16)u.w;
  o[4] = (__bf16)v.x; o[5] = (__bf16)v.y; o[6] = (__bf16)v.z; o[7] = (__bf16)v.w;
  return o;
}

// ---------------------------------------------------------------------------
// Prep kernel: fp32 -> bf16 FRAG-MAJOR swizzle of all MLP weights into d_ws,
// + zero CSR counts.
// Swizzled layout (per matrix, K = padded K-dim, src W[k][col] row-major):
//   dst[ kc*4096 + ct*512 + lane*8 + j ] = W[kc*32 + (lane>>4)*8 + j][ct*16 + (lane&15)]
// so the kernel B-load for (kc, ct) is dst + (kc*8+ct)*512 + lane*8 -> 16B/lane
// contiguous across the wave.  k >= Ksrc is zero-padded (encoder W1).
// ---------------------------------------------------------------------------
struct PrepArgs {
  const float *s_enW1, *s_enW2, *s_eeW1, *s_eeW2;
  const float *s_beW1, *s_beW2, *s_bnW1, *s_bnW2;
  __bf16 *d_enW1, *d_enW2, *d_eeW1, *d_eeW2;
  __bf16 *d_beW1, *d_beW2, *d_bnW1, *d_bnW2;
  int* counts;
};

// map swizzled flat idx (within one matrix) -> (k, col)
__device__ __forceinline__ void swz_src(int idx, int& k, int& col) {
  int j    = idx & 7;
  int lane = (idx >> 3) & 63;
  int ct   = (idx >> 9) & 7;
  int kc   = idx >> 12;
  col = ct * 16 + (lane & 15);
  k   = kc * 32 + (lane >> 4) * 8 + j;
}

__global__ __launch_bounds__(256) void prep_kernel(PrepArgs p) {
  int idx = blockIdx.x * 256 + threadIdx.x;
  int k, col;

  if (idx < 4096) {                    // enc_n_W1s (K=32, src [11][128])
    swz_src(idx, k, col);
    p.d_enW1[idx] = (__bf16)((k < 11) ? p.s_enW1[k * 128 + col] : 0.f);
    return;
  }
  idx -= 4096;
  if (idx < 16384) {                   // enc_n_W2s (K=128, src [128][128])
    swz_src(idx, k, col);
    p.d_enW2[idx] = (__bf16)p.s_enW2[k * 128 + col];
    return;
  }
  idx -= 16384;
  if (idx < 4096) {                    // enc_e_W1s (K=32, src [5][128])
    swz_src(idx, k, col);
    p.d_eeW1[idx] = (__bf16)((k < 5) ? p.s_eeW1[k * 128 + col] : 0.f);
    return;
  }
  idx -= 4096;
  if (idx < 16384) {                   // enc_e_W2s
    swz_src(idx, k, col);
    p.d_eeW2[idx] = (__bf16)p.s_eeW2[k * 128 + col];
    return;
  }
  idx -= 16384;
  if (idx < 294912) {                  // blk_e_W1s [6] (K=384, src [6][384][128])
    int s = idx / 49152, rem = idx % 49152;
    swz_src(rem, k, col);
    p.d_beW1[idx] = (__bf16)p.s_beW1[(size_t)s * 49152 + k * 128 + col];
    return;
  }
  idx -= 294912;
  if (idx < 98304) {                   // blk_e_W2s [6] (K=128)
    int s = idx >> 14, rem = idx & 16383;
    swz_src(rem, k, col);
    p.d_beW2[idx] = (__bf16)p.s_beW2[s * 16384 + k * 128 + col];
    return;
  }
  idx -= 98304;
  if (idx < 196608) {                  // blk_n_W1s [6] (K=256, src [6][256][128])
    int s = idx >> 15, rem = idx & 32767;
    swz_src(rem, k, col);
    p.d_bnW1[idx] = (__bf16)p.s_bnW1[s * 32768 + k * 128 + col];
    return;
  }
  idx -= 196608;
  if (idx < 98304) {                   // blk_n_W2s [6] (K=128)
    int s = idx >> 14, rem = idx & 16383;
    swz_src(rem, k, col);
    p.d_bnW2[idx] = (__bf16)p.s_bnW2[s * 16384 + k * 128 + col];
    return;
  }
  idx -= 98304;
  if (idx < N_NODES) p.counts[idx] = 0;   // zero CSR histogram
}

// ---- CSR build: histogram -> scan -> fill -------------------------------
__global__ __launch_bounds__(256) void hist_kernel(const int* __restrict__ recv,
                                                   int* __restrict__ counts) {
  int e = blockIdx.x * 256 + threadIdx.x;
  if (e < N_EDGES) atomicAdd(&counts[recv[e]], 1);
}

__global__ __launch_bounds__(1024) void scan_kernel(const int* __restrict__ counts,
                                                    int* __restrict__ row_ptr,
                                                    int* __restrict__ cursor) {
  __shared__ int part[1024];
  const int t = threadIdx.x;
  const int base = t * 20;
  int local[20];
  int s = 0;
#pragma unroll
  for (int i = 0; i < 20; ++i) {
    int idx = base + i;
    int v = (idx < N_NODES) ? counts[idx] : 0;
    local[i] = s;                      // exclusive within chunk
    s += v;
  }
  part[t] = s;
  __syncthreads();
  for (int off = 1; off < 1024; off <<= 1) {
    int add = (t >= off) ? part[t - off] : 0;
    __syncthreads();
    part[t] += add;
    __syncthreads();
  }
  const int excl = part[t] - s;        // exclusive prefix of this chunk
#pragma unroll
  for (int i = 0; i < 20; ++i) {
    int idx = base + i;
    if (idx < N_NODES) {
      int v = excl + local[i];
      row_ptr[idx] = v;
      cursor[idx]  = v;
    }
  }
  if (t == 1023) row_ptr[N_NODES] = part[1023];
}

__global__ __launch_bounds__(256) void fill_kernel(const int* __restrict__ recv,
                                                   int* __restrict__ cursor,
                                                   int* __restrict__ edge_list) {
  int e = blockIdx.x * 256 + threadIdx.x;
  if (e < N_EDGES) {
    int r = recv[e];
    int pos = atomicAdd(&cursor[r], 1);
    edge_list[pos] = e;
  }
}

// ---------------------------------------------------------------------------
// Aggregation kernel: one wave per node.  aggr_bf[n] = sum of new_e rows of
// incident edges (CSR).  Lanes pre-load the contiguous edge_list segment
// (64 at a time), then all 64 lanes read each 256B new_e row coalesced
// (bf16x2/lane) and accumulate fp32 in registers; coalesced bf16 store.
// ---------------------------------------------------------------------------
__global__ __launch_bounds__(256) void agg_kernel(
    const int* __restrict__ row_ptr, const int* __restrict__ edge_list,
    const __bf16* __restrict__ new_e, __bf16* __restrict__ aggr_bf) {
  const int wv   = threadIdx.x >> 6;
  const int lane = threadIdx.x & 63;
  const int n    = blockIdx.x * 4 + wv;
  if (n >= N_NODES) return;
  int p = row_ptr[n];
  const int pe = row_ptr[n + 1];
  float s0 = 0.f, s1 = 0.f;
  while (p < pe) {
    const int cnt = min(pe - p, 64);
    int eid = (lane < cnt) ? edge_list[p + lane] : 0;
    for (int j = 0; j < cnt; ++j) {
      const int e = __shfl(eid, j);
      bf16x2 v = *(const bf16x2*)(new_e + (size_t)e * LDIM + lane * 2);
      s0 += (float)v[0];
      s1 += (float)v[1];
    }
    p += cnt;
  }
  bf16x2 o;
  o[0] = (__bf16)s0; o[1] = (__bf16)s1;
  *(bf16x2*)(aggr_bf + (size_t)n * LDIM + lane * 2) = o;
}

// ---------------------------------------------------------------------------
// Fused 2-layer MLP + LayerNorm, single-wave blocks (64 threads, 32 rows).
// MODE 0: node encoder  (K1=32)  -> node_lat = y
// MODE 1: edge encoder  (K1=32)  -> edge_lat = y
// MODE 2: edge block    (K1=384) -> edge_lat = old+y (old from LDS stash);
//                                   new_e = y (bf16)
// MODE 3: node block    (K1=256, A=[node_lat|aggr_bf]) -> node_lat = old+y
// Weights FRAG-MAJOR swizzled: B-load = W + (kc*8+ct)*512 + lane*8 (coalesced).
// Layer-1 A-gathers issued in 4-kc phase batches; the phase that reads the
// residual target tees fp32 values into the ELAT LDS stash for the epilogue.
// ---------------------------------------------------------------------------
struct MlpArgs {
  const float* x; const float* mean; const float* stdv;
  float* node_lat; float* edge_lat;
  __bf16* new_e;
  const __bf16* aggr_bf;
  const int* senders; const int* receivers;
  const __bf16* W1t; const __bf16* W2t;
  const float* b1; const float* b2; const float* g; const float* beta;
  int M;
};

template <int K1, int MODE>
__global__ __launch_bounds__(64, 3) void mlp2_kernel(MlpArgs a) {
  constexpr int NKC = K1 / 32;          // K-chunks for layer 1
  constexpr int RT  = 2;                // row-tiles per wave
  constexpr int HS  = 136;              // h1 LDS strip stride (bf16)
  constexpr int ES  = 132;              // ELAT stride (fp32): 2-way alias max
  constexpr int ESZ = (MODE >= 2) ? 32 * ES : 4;   // stash only for MODE 2/3

  __shared__ __align__(16) __bf16 H1[32 * HS];     // 8704 B
  __shared__ __align__(16) float  ELAT[ESZ];       // 16896 B (MODE 2/3)

  const int lane  = threadIdx.x & 63;
  const int l15   = lane & 15;
  const int quad  = lane >> 4;
  const int M     = a.M;
  const int rbase = blockIdx.x * 32;             // wave's first row

  __bf16* h1w = H1;

  // rows this lane stages as A (one per row-tile)
  int rowA[RT];
#pragma unroll
  for (int rt = 0; rt < RT; ++rt) {
    int r = rbase + rt * 16 + l15;
    rowA[rt] = (r < M) ? r : (M - 1);
  }

  int sA[RT], rA[RT];
  if constexpr (MODE == 2) {
#pragma unroll
    for (int rt = 0; rt < RT; ++rt) {
      sA[rt] = a.senders[rowA[rt]];
      rA[rt] = a.receivers[rowA[rt]];
    }
  }

  f32x4 acc[RT][8];
#pragma unroll
  for (int rt = 0; rt < RT; ++rt)
#pragma unroll
    for (int i = 0; i < 8; ++i) acc[rt][i] = (f32x4)(0.f);

  // ---- layer 1: [32,K1] x [K1,128] ----
  if constexpr (MODE == 0 || MODE == 1) {
    constexpr int KIN = (MODE == 0) ? 11 : 5;
    bf16x8 af[RT];
#pragma unroll
    for (int rt = 0; rt < RT; ++rt) {
      const float* xr = a.x + (size_t)rowA[rt] * KIN;
#pragma unroll
      for (int j = 0; j < 8; ++j) {
        int c = quad * 8 + j;
        float v = (c < KIN) ? (xr[c] - a.mean[c]) / a.stdv[c] : 0.f;
        af[rt][j] = (__bf16)v;
      }
    }
    bf16x8 bfv[8];
#pragma unroll
    for (int ct = 0; ct < 8; ++ct)
      bfv[ct] = *(const bf16x8*)(a.W1t + (ct * 64 + lane) * 8);
#pragma unroll
    for (int rt = 0; rt < RT; ++rt)
#pragma unroll
      for (int ct = 0; ct < 8; ++ct)
        acc[rt][ct] = __builtin_amdgcn_mfma_f32_16x16x32_bf16(af[rt], bfv[ct], acc[rt][ct], 0, 0, 0);
  } else {
    constexpr int NPH = NKC / 4;        // phases of 4 kc
#pragma unroll
    for (int ph = 0; ph < NPH; ++ph) {
      // batch all 8 A-gathers of this phase (the random-latency loads);
      // the residual-target phase also tees fp32 into the ELAT stash.
      constexpr int STASH_PH = (MODE == 2) ? 2 : 0;
      bf16x8 afr[RT][4];
#pragma unroll
      for (int kk = 0; kk < 4; ++kk) {
#pragma unroll
        for (int rt = 0; rt < RT; ++rt) {
          const float* src;
          bool stash = false;
          if constexpr (MODE == 2) {
            src = (ph == 0) ? (a.node_lat + (size_t)sA[rt] * LDIM)
                : (ph == 1) ? (a.node_lat + (size_t)rA[rt] * LDIM)
                            : (a.edge_lat + (size_t)rowA[rt] * LDIM);
            stash = (ph == STASH_PH);
          } else {  // MODE 3
            if (ph == 0) { src = a.node_lat + (size_t)rowA[rt] * LDIM; stash = true; }
            else {
              afr[rt][kk] = *(const bf16x8*)(a.aggr_bf + (size_t)rowA[rt] * LDIM + kk * 32 + quad * 8);
              continue;
            }
          }
          const float* p = src + kk * 32 + quad * 8;
          float4 u = *(const float4*)p;
          float4 v = *(const float4*)(p + 4);
          if (stash) {
            float* ep = &ELAT[(rt * 16 + l15) * ES + kk * 32 + quad * 8];
            *(float4*)ep       = u;
            *(float4*)(ep + 4) = v;
          }
          bf16x8 o;
          o[0] = (__bf16)u.x; o[1] = (__bf16)u.y; o[2] = (__bf16)u.z; o[3] = (__bf16)u.w;
          o[4] = (__bf16)v.x; o[5] = (__bf16)v.y; o[6] = (__bf16)v.z; o[7] = (__bf16)v.w;
          afr[rt][kk] = o;
        }
      }
#pragma unroll
      for (int kk = 0; kk < 4; ++kk) {
        const int kc = ph * 4 + kk;
        bf16x8 bfv[8];
#pragma unroll
        for (int ct = 0; ct < 8; ++ct)   // frag-major: 16B/lane, coalesced
          bfv[ct] = *(const bf16x8*)(a.W1t + ((kc * 8 + ct) * 64 + lane) * 8);
#pragma unroll
        for (int rt = 0; rt < RT; ++rt)
#pragma unroll
          for (int ct = 0; ct < 8; ++ct)
            acc[rt][ct] = __builtin_amdgcn_mfma_f32_16x16x32_bf16(afr[rt][kk], bfv[ct], acc[rt][ct], 0, 0, 0);
      }
    }
  }

  // ---- h1 = relu(acc+b1) -> LDS strip (C/D layout -> row-major) ----
#pragma unroll
  for (int ct = 0; ct < 8; ++ct) {
    const float bb = a.b1[ct * 16 + l15];
#pragma unroll
    for (int rt = 0; rt < RT; ++rt)
#pragma unroll
      for (int rr = 0; rr < 4; ++rr) {
        float v = fmaxf(acc[rt][ct][rr] + bb, 0.f);
        h1w[(rt * 16 + quad * 4 + rr) * HS + ct * 16 + l15] = (__bf16)v;
      }
  }
  // same-wave DS ordering: writes before reads in program order.

  // ---- layer 2: [32,128] x [128,128] ----
#pragma unroll
  for (int rt = 0; rt < RT; ++rt)
#pragma unroll
    for (int i = 0; i < 8; ++i) acc[rt][i] = (f32x4)(0.f);

#pragma unroll
  for (int kc = 0; kc < 4; ++kc) {
    bf16x8 af[RT];
#pragma unroll
    for (int rt = 0; rt < RT; ++rt)
      af[rt] = *(const bf16x8*)(h1w + (rt * 16 + l15) * HS + kc * 32 + quad * 8);
    bf16x8 bfv[8];
#pragma unroll
    for (int ct = 0; ct < 8; ++ct)     // frag-major: 16B/lane, coalesced
      bfv[ct] = *(const bf16x8*)(a.W2t + ((kc * 8 + ct) * 64 + lane) * 8);
#pragma unroll
    for (int rt = 0; rt < RT; ++rt)
#pragma unroll
      for (int ct = 0; ct < 8; ++ct)
        acc[rt][ct] = __builtin_amdgcn_mfma_f32_16x16x32_bf16(af[rt], bfv[ct], acc[rt][ct], 0, 0, 0);
  }

  // ---- h2 = relu(acc+b2), LayerNorm in registers (shuffle over 16 lanes) ----
#pragma unroll
  for (int ct = 0; ct < 8; ++ct) {
    const float bb = a.b2[ct * 16 + l15];
#pragma unroll
    for (int rt = 0; rt < RT; ++rt)
#pragma unroll
      for (int rr = 0; rr < 4; ++rr)
        acc[rt][ct][rr] = fmaxf(acc[rt][ct][rr] + bb, 0.f);
  }

  float mu[RT][4], rs[RT][4];
#pragma unroll
  for (int rt = 0; rt < RT; ++rt)
#pragma unroll
    for (int rr = 0; rr < 4; ++rr) {
      float s = 0.f, s2 = 0.f;
#pragma unroll
      for (int ct = 0; ct < 8; ++ct) { float v = acc[rt][ct][rr]; s += v; s2 += v * v; }
      s  += __shfl_xor(s, 1);  s2 += __shfl_xor(s2, 1);
      s  += __shfl_xor(s, 2);  s2 += __shfl_xor(s2, 2);
      s  += __shfl_xor(s, 4);  s2 += __shfl_xor(s2, 4);
      s  += __shfl_xor(s, 8);  s2 += __shfl_xor(s2, 8);
      float m = s * (1.f / 128.f);
      float var = fmaxf(s2 * (1.f / 128.f) - m * m, 0.f);
      mu[rt][rr] = m; rs[rt][rr] = rsqrtf(var + 1e-5f);
    }

  float gv[8], bev[8];
#pragma unroll
  for (int ct = 0; ct < 8; ++ct) {
    gv[ct]  = a.g[ct * 16 + l15];
    bev[ct] = a.beta[ct * 16 + l15];
  }

  // ---- epilogue (guarded rows; residual old-value from LDS stash) ----
#pragma unroll
  for (int rt = 0; rt < RT; ++rt)
#pragma unroll
    for (int rr = 0; rr < 4; ++rr) {
      const int row = rbase + rt * 16 + quad * 4 + rr;
      if (row >= M) continue;
      if constexpr (MODE == 2) {
#pragma unroll
        for (int ct = 0; ct < 8; ++ct) {
          const int col = ct * 16 + l15;
          float y = (acc[rt][ct][rr] - mu[rt][rr]) * rs[rt][rr] * gv[ct] + bev[ct];
          float old = ELAT[(rt * 16 + quad * 4 + rr) * ES + col];
          a.edge_lat[(size_t)row * LDIM + col] = old + y;            // pure store
          a.new_e[(size_t)row * LDIM + col] = (__bf16)y;             // for agg
        }
      } else if constexpr (MODE == 3) {
#pragma unroll
        for (int ct = 0; ct < 8; ++ct) {
          const int col = ct * 16 + l15;
          float y = (acc[rt][ct][rr] - mu[rt][rr]) * rs[rt][rr] * gv[ct] + bev[ct];
          float old = ELAT[(rt * 16 + quad * 4 + rr) * ES + col];
          a.node_lat[(size_t)row * LDIM + col] = old + y;            // pure store
        }
      } else {
#pragma unroll
        for (int ct = 0; ct < 8; ++ct) {
          const int col = ct * 16 + l15;
          float y = (acc[rt][ct][rr] - mu[rt][rr]) * rs[rt][rr] * gv[ct] + bev[ct];
          if constexpr (MODE == 0) a.node_lat[(size_t)row * LDIM + col] = y;
          else                     a.edge_lat[(size_t)row * LDIM + col] = y;
        }
      }
    }
}

// ---------------------------------------------------------------------------
// Decoder: h = swish(node_lat @ W1 + b1); dec = h @ W2 + b2; out[t,n] = dec*dt
// Processes 64 nodes per block -> needs its own grid size (DEC_BLOCKS).
// ---------------------------------------------------------------------------
__global__ __launch_bounds__(256) void decode_kernel(
    const float* __restrict__ node_lat,
    const float* __restrict__ W1, const float* __restrict__ b1,
    const float* __restrict__ W2, const float* __restrict__ b2,
    float* __restrict__ out) {
  __shared__ float X[64][129];
  const int n0 = blockIdx.x * 64;
  for (int idx = threadIdx.x; idx < 64 * 32; idx += 256) {
    int r = idx >> 5, c4 = idx & 31;
    int n = n0 + r; if (n >= N_NODES) n = N_NODES - 1;
    float4 v = *((const float4*)(node_lat + (size_t)n * 128) + c4);
    X[r][c4 * 4 + 0] = v.x; X[r][c4 * 4 + 1] = v.y;
    X[r][c4 * 4 + 2] = v.z; X[r][c4 * 4 + 3] = v.w;
  }
  __syncthreads();
  const int r = threadIdx.x;
  if (r < 64) {
    const int n = n0 + r;
    if (n < N_NODES) {
      float h[8];
#pragma unroll
      for (int j = 0; j < 8; ++j) h[j] = b1[j];
      for (int k = 0; k < 128; ++k) {
        float xv = X[r][k];
#pragma unroll
        for (int j = 0; j < 8; ++j) h[j] = fmaf(xv, W1[k * 8 + j], h[j]);
      }
#pragma unroll
      for (int j = 0; j < 8; ++j) h[j] = h[j] / (1.f + expf(-h[j]));  // swish
#pragma unroll
      for (int t = 0; t < 5; ++t) {
        float d = b2[t];
#pragma unroll
        for (int j = 0; j < 8; ++j) d = fmaf(h[j], W2[j * 5 + t], d);
        out[t * N_NODES + n] = d * (float)(t + 1);
      }
    }
  }
}

// ---------------------------------------------------------------------------
extern "C" void kernel_launch(void* const* d_in, const int* in_sizes, int n_in,
                              void* d_out, int out_size, void* d_ws, size_t ws_size,
                              hipStream_t stream) {
  (void)in_sizes; (void)n_in; (void)out_size; (void)ws_size;

  const float* node_features = (const float*)d_in[0];
  const float* edge_features = (const float*)d_in[1];
  const int*   senders       = (const int*)d_in[2];
  const int*   receivers     = (const int*)d_in[3];
  const float* node_mean = (const float*)d_in[4];
  const float* node_std  = (const float*)d_in[5];
  const float* edge_mean = (const float*)d_in[6];
  const float* edge_std  = (const float*)d_in[7];
  const float* enc_n_W1 = (const float*)d_in[8];
  const float* enc_n_b1 = (const float*)d_in[9];
  const float* enc_n_W2 = (const float*)d_in[10];
  const float* enc_n_b2 = (const float*)d_in[11];
  const float* enc_n_g    = (const float*)d_in[12];
  const float* enc_n_beta = (const float*)d_in[13];
  const float* enc_e_W1 = (const float*)d_in[14];
  const float* enc_e_b1 = (const float*)d_in[15];
  const float* enc_e_W2 = (const float*)d_in[16];
  const float* enc_e_b2 = (const float*)d_in[17];
  const float* enc_e_g    = (const float*)d_in[18];
  const float* enc_e_beta = (const float*)d_in[19];
  const float* blk_e_W1 = (const float*)d_in[20];
  const float* blk_e_b1 = (const float*)d_in[21];
  const float* blk_e_W2 = (const float*)d_in[22];
  const float* blk_e_b2 = (const float*)d_in[23];
  const float* blk_e_g    = (const float*)d_in[24];
  const float* blk_e_beta = (const float*)d_in[25];
  const float* blk_n_W1 = (const float*)d_in[26];
  const float* blk_n_b1 = (const float*)d_in[27];
  const float* blk_n_W2 = (const float*)d_in[28];
  const float* blk_n_b2 = (const float*)d_in[29];
  const float* blk_n_g    = (const float*)d_in[30];
  const float* blk_n_beta = (const float*)d_in[31];
  const float* dec_W1 = (const float*)d_in[32];
  const float* dec_b1 = (const float*)d_in[33];
  const float* dec_W2 = (const float*)d_in[34];
  const float* dec_b2 = (const float*)d_in[35];

  // ---- workspace layout (bytes, all 16B-aligned) ----
  char* ws = (char*)d_ws;
  float*  node_lat = (float*)(ws);                   // 10,240,000
  float*  edge_lat = (float*)(ws + 10240000);        // 51,200,000
  __bf16* new_e    = (__bf16*)(ws + 61440000);       // 25,600,000 (bf16 E x 128)
  __bf16* wb       = (__bf16*)(ws + 87040000);       // 1,458,176 (bf16 weights)
  int* counts    = (int*)(ws + 88498176);            // 80,000
  int* row_ptr   = (int*)(ws + 88578176);            // 80,004
  int* cursor    = (int*)(ws + 88658192);            // 80,000
  int* edge_list = (int*)(ws + 88738192);            // 400,000
  __bf16* aggr_bf = (__bf16*)(ws + 89138192);        // 5,120,000 -> ends 94,258,192

  __bf16* enW1s = wb;                    // 128*32
  __bf16* enW2s = enW1s + 4096;          // 128*128
  __bf16* eeW1s = enW2s + 16384;         // 128*32
  __bf16* eeW2s = eeW1s + 4096;          // 128*128
  __bf16* beW1s = eeW2s + 16384;         // 6*128*384
  __bf16* beW2s = beW1s + 6 * 49152;     // 6*128*128
  __bf16* bnW1s = beW2s + 6 * 16384;     // 6*128*256
  __bf16* bnW2s = bnW1s + 6 * 32768;     // 6*128*128

  // ---- prep: weight frag-major swizzle + zero CSR counts ----
  PrepArgs pa;
  pa.s_enW1 = enc_n_W1; pa.s_enW2 = enc_n_W2; pa.s_eeW1 = enc_e_W1; pa.s_eeW2 = enc_e_W2;
  pa.s_beW1 = blk_e_W1; pa.s_beW2 = blk_e_W2; pa.s_bnW1 = blk_n_W1; pa.s_bnW2 = blk_n_W2;
  pa.d_enW1 = enW1s; pa.d_enW2 = enW2s; pa.d_eeW1 = eeW1s; pa.d_eeW2 = eeW2s;
  pa.d_beW1 = beW1s; pa.d_beW2 = beW2s; pa.d_bnW1 = bnW1s; pa.d_bnW2 = bnW2s;
  pa.counts = counts;
  prep_kernel<<<2927, 256, 0, stream>>>(pa);   // 729,088 weight elems + 20,000

  // ---- CSR build ----
  hist_kernel<<<(N_EDGES + 255) / 256, 256, 0, stream>>>(receivers, counts);
  scan_kernel<<<1, 1024, 0, stream>>>(counts, row_ptr, cursor);
  fill_kernel<<<(N_EDGES + 255) / 256, 256, 0, stream>>>(receivers, cursor, edge_list);

  const int NODE_BLOCKS = (N_NODES + 31) / 32;     // 625 (mlp2: 32 rows/block, 1 wave)
  const int EDGE_BLOCKS = (N_EDGES + 31) / 32;     // 3125
  const int DEC_BLOCKS  = (N_NODES + 63) / 64;     // 313 (decode: 64 rows/block)
  const int AGG_BLOCKS  = (N_NODES + 3) / 4;       // 5000 (agg: 4 nodes/block)

  MlpArgs base;
  base.node_lat = node_lat; base.edge_lat = edge_lat; base.new_e = new_e;
  base.aggr_bf = aggr_bf;
  base.senders = senders; base.receivers = receivers;
  base.x = nullptr; base.mean = nullptr; base.stdv = nullptr;

  // ---- encoders ----
  {
    MlpArgs a = base;
    a.x = node_features; a.mean = node_mean; a.stdv = node_std;
    a.W1t = enW1s; a.W2t = enW2s;
    a.b1 = enc_n_b1; a.b2 = enc_n_b2; a.g = enc_n_g; a.beta = enc_n_beta;
    a.M = N_NODES;
    mlp2_kernel<32, 0><<<NODE_BLOCKS, 64, 0, stream>>>(a);
  }
  {
    MlpArgs a = base;
    a.x = edge_features; a.mean = edge_mean; a.stdv = edge_std;
    a.W1t = eeW1s; a.W2t = eeW2s;
    a.b1 = enc_e_b1; a.b2 = enc_e_b2; a.g = enc_e_g; a.beta = enc_e_beta;
    a.M = N_EDGES;
    mlp2_kernel<32, 1><<<EDGE_BLOCKS, 64, 0, stream>>>(a);
  }

  // ---- message-passing steps ----
  for (int i = 0; i < NSTEPS; ++i) {
    {
      MlpArgs a = base;
      a.W1t = beW1s + (size_t)i * 49152; a.W2t = beW2s + (size_t)i * 16384;
      a.b1 = blk_e_b1 + i * 128; a.b2 = blk_e_b2 + i * 128;
      a.g = blk_e_g + i * 128; a.beta = blk_e_beta + i * 128;
      a.M = N_EDGES;
      mlp2_kernel<384, 2><<<EDGE_BLOCKS, 64, 0, stream>>>(a);
    }
    agg_kernel<<<AGG_BLOCKS, 256, 0, stream>>>(row_ptr, edge_list, new_e, aggr_bf);
    {
      MlpArgs a = base;
      a.W1t = bnW1s + (size_t)i * 32768; a.W2t = bnW2s + (size_t)i * 16384;
      a.b1 = blk_n_b1 + i * 128; a.b2 = blk_n_b2 + i * 128;
      a.g = blk_n_g + i * 128; a.beta = blk_n_beta + i * 128;
      a.M = N_NODES;
      mlp2_kernel<256, 3><<<NODE_BLOCKS, 64, 0, stream>>>(a);
    }
  }

  // ---- decoder ----
  decode_kernel<<<DEC_BLOCKS, 256, 0, stream>>>(
      node_lat, dec_W1, dec_b1, dec_W2, dec_b2, (float*)d_out);
}

// Round 12
// 705.256 us; speedup vs baseline: 1.1444x; 1.1444x over previous
//
#include <hip/hip_runtime.h>
#include <cstdint>
#include <cstddef>

// ---------------------------------------------------------------------------
// EncodeProcessDecode (MeshGraphNets-style GNN) on gfx950.
// N=20000 nodes, E=100000 edges, L=128, S=6 steps.
// Round 12 = r10 structure (r11's LDS stash reverted: FETCH dropped as
// predicted but LDS 25.6KB + VGPR 136 halved occupancy -> dur regressed;
// lesson: occupancy > L2-absorbable traffic here) + bf16 node_lat mirror:
// edge-kernel random gathers read node_bf (bf16) instead of fp32 node_lat --
// BIT-IDENTICAL (values were rounded to bf16 via cvt8 anyway), half the
// gather bytes, hot set 10.2->5.1MB (≈L2-resident), no cvt in hot loop.
// Kept: single-wave blocks + phase-batched gathers (r10), RT=2 (r9 lesson),
// frag-major weights (r7), agg kernel (r8), scalar epilogue (r6 lesson).
// ---------------------------------------------------------------------------

#define N_NODES 20000
#define N_EDGES 100000
#define LDIM    128
#define NSTEPS  6

typedef float  f32x4  __attribute__((ext_vector_type(4)));
typedef __bf16 bf16x8 __attribute__((ext_vector_type(8)));
typedef __bf16 bf16x2 __attribute__((ext_vector_type(2)));

// load 8 consecutive fp32, round to bf16x8 (one MFMA A-frag chunk)
__device__ __forceinline__ bf16x8 cvt8(const float* p) {
  float4 u = *(const float4*)p;
  float4 v = *(const float4*)(p + 4);
  bf16x8 o;
  o[0] = (__bf16)u.x; o[1] = (__bf16)u.y; o[2] = (__bf16)u.z; o[3] = (__bf16)u.w;
  o[4] = (__bf16)v.x; o[5] = (__bf16)v.y; o[6] = (__bf16)v.z; o[7] = (__bf16)v.w;
  return o;
}

// ---------------------------------------------------------------------------
// Prep kernel: fp32 -> bf16 FRAG-MAJOR swizzle of all MLP weights into d_ws,
// + zero CSR counts.
// Swizzled layout (per matrix, K = padded K-dim, src W[k][col] row-major):
//   dst[ kc*4096 + ct*512 + lane*8 + j ] = W[kc*32 + (lane>>4)*8 + j][ct*16 + (lane&15)]
// so the kernel B-load for (kc, ct) is dst + (kc*8+ct)*512 + lane*8 -> 16B/lane
// contiguous across the wave.  k >= Ksrc is zero-padded (encoder W1).
// ---------------------------------------------------------------------------
struct PrepArgs {
  const float *s_enW1, *s_enW2, *s_eeW1, *s_eeW2;
  const float *s_beW1, *s_beW2, *s_bnW1, *s_bnW2;
  __bf16 *d_enW1, *d_enW2, *d_eeW1, *d_eeW2;
  __bf16 *d_beW1, *d_beW2, *d_bnW1, *d_bnW2;
  int* counts;
};

// map swizzled flat idx (within one matrix) -> (k, col)
__device__ __forceinline__ void swz_src(int idx, int& k, int& col) {
  int j    = idx & 7;
  int lane = (idx >> 3) & 63;
  int ct   = (idx >> 9) & 7;
  int kc   = idx >> 12;
  col = ct * 16 + (lane & 15);
  k   = kc * 32 + (lane >> 4) * 8 + j;
}

__global__ __launch_bounds__(256) void prep_kernel(PrepArgs p) {
  int idx = blockIdx.x * 256 + threadIdx.x;
  int k, col;

  if (idx < 4096) {                    // enc_n_W1s (K=32, src [11][128])
    swz_src(idx, k, col);
    p.d_enW1[idx] = (__bf16)((k < 11) ? p.s_enW1[k * 128 + col] : 0.f);
    return;
  }
  idx -= 4096;
  if (idx < 16384) {                   // enc_n_W2s (K=128, src [128][128])
    swz_src(idx, k, col);
    p.d_enW2[idx] = (__bf16)p.s_enW2[k * 128 + col];
    return;
  }
  idx -= 16384;
  if (idx < 4096) {                    // enc_e_W1s (K=32, src [5][128])
    swz_src(idx, k, col);
    p.d_eeW1[idx] = (__bf16)((k < 5) ? p.s_eeW1[k * 128 + col] : 0.f);
    return;
  }
  idx -= 4096;
  if (idx < 16384) {                   // enc_e_W2s
    swz_src(idx, k, col);
    p.d_eeW2[idx] = (__bf16)p.s_eeW2[k * 128 + col];
    return;
  }
  idx -= 16384;
  if (idx < 294912) {                  // blk_e_W1s [6] (K=384, src [6][384][128])
    int s = idx / 49152, rem = idx % 49152;
    swz_src(rem, k, col);
    p.d_beW1[idx] = (__bf16)p.s_beW1[(size_t)s * 49152 + k * 128 + col];
    return;
  }
  idx -= 294912;
  if (idx < 98304) {                   // blk_e_W2s [6] (K=128)
    int s = idx >> 14, rem = idx & 16383;
    swz_src(rem, k, col);
    p.d_beW2[idx] = (__bf16)p.s_beW2[s * 16384 + k * 128 + col];
    return;
  }
  idx -= 98304;
  if (idx < 196608) {                  // blk_n_W1s [6] (K=256, src [6][256][128])
    int s = idx >> 15, rem = idx & 32767;
    swz_src(rem, k, col);
    p.d_bnW1[idx] = (__bf16)p.s_bnW1[s * 32768 + k * 128 + col];
    return;
  }
  idx -= 196608;
  if (idx < 98304) {                   // blk_n_W2s [6] (K=128)
    int s = idx >> 14, rem = idx & 16383;
    swz_src(rem, k, col);
    p.d_bnW2[idx] = (__bf16)p.s_bnW2[s * 16384 + k * 128 + col];
    return;
  }
  idx -= 98304;
  if (idx < N_NODES) p.counts[idx] = 0;   // zero CSR histogram
}

// ---- CSR build: histogram -> scan -> fill -------------------------------
__global__ __launch_bounds__(256) void hist_kernel(const int* __restrict__ recv,
                                                   int* __restrict__ counts) {
  int e = blockIdx.x * 256 + threadIdx.x;
  if (e < N_EDGES) atomicAdd(&counts[recv[e]], 1);
}

__global__ __launch_bounds__(1024) void scan_kernel(const int* __restrict__ counts,
                                                    int* __restrict__ row_ptr,
                                                    int* __restrict__ cursor) {
  __shared__ int part[1024];
  const int t = threadIdx.x;
  const int base = t * 20;
  int local[20];
  int s = 0;
#pragma unroll
  for (int i = 0; i < 20; ++i) {
    int idx = base + i;
    int v = (idx < N_NODES) ? counts[idx] : 0;
    local[i] = s;                      // exclusive within chunk
    s += v;
  }
  part[t] = s;
  __syncthreads();
  for (int off = 1; off < 1024; off <<= 1) {
    int add = (t >= off) ? part[t - off] : 0;
    __syncthreads();
    part[t] += add;
    __syncthreads();
  }
  const int excl = part[t] - s;        // exclusive prefix of this chunk
#pragma unroll
  for (int i = 0; i < 20; ++i) {
    int idx = base + i;
    if (idx < N_NODES) {
      int v = excl + local[i];
      row_ptr[idx] = v;
      cursor[idx]  = v;
    }
  }
  if (t == 1023) row_ptr[N_NODES] = part[1023];
}

__global__ __launch_bounds__(256) void fill_kernel(const int* __restrict__ recv,
                                                   int* __restrict__ cursor,
                                                   int* __restrict__ edge_list) {
  int e = blockIdx.x * 256 + threadIdx.x;
  if (e < N_EDGES) {
    int r = recv[e];
    int pos = atomicAdd(&cursor[r], 1);
    edge_list[pos] = e;
  }
}

// ---------------------------------------------------------------------------
// Aggregation kernel: one wave per node.  aggr_bf[n] = sum of new_e rows of
// incident edges (CSR).  Lanes pre-load the contiguous edge_list segment
// (64 at a time), then all 64 lanes read each 256B new_e row coalesced
// (bf16x2/lane) and accumulate fp32 in registers; coalesced bf16 store.
// ---------------------------------------------------------------------------
__global__ __launch_bounds__(256) void agg_kernel(
    const int* __restrict__ row_ptr, const int* __restrict__ edge_list,
    const __bf16* __restrict__ new_e, __bf16* __restrict__ aggr_bf) {
  const int wv   = threadIdx.x >> 6;
  const int lane = threadIdx.x & 63;
  const int n    = blockIdx.x * 4 + wv;
  if (n >= N_NODES) return;
  int p = row_ptr[n];
  const int pe = row_ptr[n + 1];
  float s0 = 0.f, s1 = 0.f;
  while (p < pe) {
    const int cnt = min(pe - p, 64);
    int eid = (lane < cnt) ? edge_list[p + lane] : 0;
    for (int j = 0; j < cnt; ++j) {
      const int e = __shfl(eid, j);
      bf16x2 v = *(const bf16x2*)(new_e + (size_t)e * LDIM + lane * 2);
      s0 += (float)v[0];
      s1 += (float)v[1];
    }
    p += cnt;
  }
  bf16x2 o;
  o[0] = (__bf16)s0; o[1] = (__bf16)s1;
  *(bf16x2*)(aggr_bf + (size_t)n * LDIM + lane * 2) = o;
}

// ---------------------------------------------------------------------------
// Fused 2-layer MLP + LayerNorm, single-wave blocks (64 threads, 32 rows).
// MODE 0: node encoder  (K1=32)  -> node_lat = y; node_bf = bf16(y)
// MODE 1: edge encoder  (K1=32)  -> edge_lat = y
// MODE 2: edge block    (K1=384, A=[node_bf(s)|node_bf(r)|edge_lat])
//                                -> edge_lat += y; new_e = y (bf16)
// MODE 3: node block    (K1=256, A=[node_bf|aggr_bf]) -> node_lat += y;
//                                   node_bf = bf16(node_lat)
// Weights FRAG-MAJOR swizzled: B-load = W + (kc*8+ct)*512 + lane*8 (coalesced).
// Layer-1 A-gathers issued in 4-kc phase batches (deep latency overlap);
// node-row gathers read the bf16 mirror (bit-identical to cvt8(fp32)).
// ---------------------------------------------------------------------------
struct MlpArgs {
  const float* x; const float* mean; const float* stdv;
  float* node_lat; float* edge_lat;
  __bf16* new_e;
  const __bf16* aggr_bf;
  __bf16* node_bf;
  const int* senders; const int* receivers;
  const __bf16* W1t; const __bf16* W2t;
  const float* b1; const float* b2; const float* g; const float* beta;
  int M;
};

template <int K1, int MODE>
__global__ __launch_bounds__(64, 3) void mlp2_kernel(MlpArgs a) {
  constexpr int NKC = K1 / 32;          // K-chunks for layer 1
  constexpr int RT  = 2;                // row-tiles per wave
  constexpr int HS  = 136;              // LDS strip stride (bf16)

  __shared__ __align__(16) __bf16 H1[32 * HS];   // 8704 B (one wave/block)

  const int lane  = threadIdx.x & 63;
  const int l15   = lane & 15;
  const int quad  = lane >> 4;
  const int M     = a.M;
  const int rbase = blockIdx.x * 32;             // wave's first row

  __bf16* h1w = H1;

  // rows this lane stages as A (one per row-tile)
  int rowA[RT];
#pragma unroll
  for (int rt = 0; rt < RT; ++rt) {
    int r = rbase + rt * 16 + l15;
    rowA[rt] = (r < M) ? r : (M - 1);
  }

  int sA[RT], rA[RT];
  if constexpr (MODE == 2) {
#pragma unroll
    for (int rt = 0; rt < RT; ++rt) {
      sA[rt] = a.senders[rowA[rt]];
      rA[rt] = a.receivers[rowA[rt]];
    }
  }

  f32x4 acc[RT][8];
#pragma unroll
  for (int rt = 0; rt < RT; ++rt)
#pragma unroll
    for (int i = 0; i < 8; ++i) acc[rt][i] = (f32x4)(0.f);

  // ---- layer 1: [32,K1] x [K1,128] ----
  if constexpr (MODE == 0 || MODE == 1) {
    constexpr int KIN = (MODE == 0) ? 11 : 5;
    bf16x8 af[RT];
#pragma unroll
    for (int rt = 0; rt < RT; ++rt) {
      const float* xr = a.x + (size_t)rowA[rt] * KIN;
#pragma unroll
      for (int j = 0; j < 8; ++j) {
        int c = quad * 8 + j;
        float v = (c < KIN) ? (xr[c] - a.mean[c]) / a.stdv[c] : 0.f;
        af[rt][j] = (__bf16)v;
      }
    }
    bf16x8 bfv[8];
#pragma unroll
    for (int ct = 0; ct < 8; ++ct)
      bfv[ct] = *(const bf16x8*)(a.W1t + (ct * 64 + lane) * 8);
#pragma unroll
    for (int rt = 0; rt < RT; ++rt)
#pragma unroll
      for (int ct = 0; ct < 8; ++ct)
        acc[rt][ct] = __builtin_amdgcn_mfma_f32_16x16x32_bf16(af[rt], bfv[ct], acc[rt][ct], 0, 0, 0);
  } else {
    constexpr int NPH = NKC / 4;        // phases of 4 kc
#pragma unroll
    for (int ph = 0; ph < NPH; ++ph) {
      // batch all 8 A-gathers of this phase (the random-latency loads)
      bf16x8 afr[RT][4];
#pragma unroll
      for (int kk = 0; kk < 4; ++kk) {
#pragma unroll
        for (int rt = 0; rt < RT; ++rt) {
          if constexpr (MODE == 2) {
            if (ph == 0)
              afr[rt][kk] = *(const bf16x8*)(a.node_bf + (size_t)sA[rt] * LDIM + kk * 32 + quad * 8);
            else if (ph == 1)
              afr[rt][kk] = *(const bf16x8*)(a.node_bf + (size_t)rA[rt] * LDIM + kk * 32 + quad * 8);
            else
              afr[rt][kk] = cvt8(a.edge_lat + (size_t)rowA[rt] * LDIM + kk * 32 + quad * 8);
          } else {  // MODE 3
            if (ph == 0)
              afr[rt][kk] = *(const bf16x8*)(a.node_bf + (size_t)rowA[rt] * LDIM + kk * 32 + quad * 8);
            else
              afr[rt][kk] = *(const bf16x8*)(a.aggr_bf + (size_t)rowA[rt] * LDIM + kk * 32 + quad * 8);
          }
        }
      }
#pragma unroll
      for (int kk = 0; kk < 4; ++kk) {
        const int kc = ph * 4 + kk;
        bf16x8 bfv[8];
#pragma unroll
        for (int ct = 0; ct < 8; ++ct)   // frag-major: 16B/lane, coalesced
          bfv[ct] = *(const bf16x8*)(a.W1t + ((kc * 8 + ct) * 64 + lane) * 8);
#pragma unroll
        for (int rt = 0; rt < RT; ++rt)
#pragma unroll
          for (int ct = 0; ct < 8; ++ct)
            acc[rt][ct] = __builtin_amdgcn_mfma_f32_16x16x32_bf16(afr[rt][kk], bfv[ct], acc[rt][ct], 0, 0, 0);
      }
    }
  }

  // ---- h1 = relu(acc+b1) -> LDS strip (C/D layout -> row-major) ----
#pragma unroll
  for (int ct = 0; ct < 8; ++ct) {
    const float bb = a.b1[ct * 16 + l15];
#pragma unroll
    for (int rt = 0; rt < RT; ++rt)
#pragma unroll
      for (int rr = 0; rr < 4; ++rr) {
        float v = fmaxf(acc[rt][ct][rr] + bb, 0.f);
        h1w[(rt * 16 + quad * 4 + rr) * HS + ct * 16 + l15] = (__bf16)v;
      }
  }
  // same-wave DS ordering: writes before reads in program order.

  // ---- layer 2: [32,128] x [128,128] ----
#pragma unroll
  for (int rt = 0; rt < RT; ++rt)
#pragma unroll
    for (int i = 0; i < 8; ++i) acc[rt][i] = (f32x4)(0.f);

#pragma unroll
  for (int kc = 0; kc < 4; ++kc) {
    bf16x8 af[RT];
#pragma unroll
    for (int rt = 0; rt < RT; ++rt)
      af[rt] = *(const bf16x8*)(h1w + (rt * 16 + l15) * HS + kc * 32 + quad * 8);
    bf16x8 bfv[8];
#pragma unroll
    for (int ct = 0; ct < 8; ++ct)     // frag-major: 16B/lane, coalesced
      bfv[ct] = *(const bf16x8*)(a.W2t + ((kc * 8 + ct) * 64 + lane) * 8);
#pragma unroll
    for (int rt = 0; rt < RT; ++rt)
#pragma unroll
      for (int ct = 0; ct < 8; ++ct)
        acc[rt][ct] = __builtin_amdgcn_mfma_f32_16x16x32_bf16(af[rt], bfv[ct], acc[rt][ct], 0, 0, 0);
  }

  // ---- h2 = relu(acc+b2), LayerNorm in registers (shuffle over 16 lanes) ----
#pragma unroll
  for (int ct = 0; ct < 8; ++ct) {
    const float bb = a.b2[ct * 16 + l15];
#pragma unroll
    for (int rt = 0; rt < RT; ++rt)
#pragma unroll
      for (int rr = 0; rr < 4; ++rr)
        acc[rt][ct][rr] = fmaxf(acc[rt][ct][rr] + bb, 0.f);
  }

  float mu[RT][4], rs[RT][4];
#pragma unroll
  for (int rt = 0; rt < RT; ++rt)
#pragma unroll
    for (int rr = 0; rr < 4; ++rr) {
      float s = 0.f, s2 = 0.f;
#pragma unroll
      for (int ct = 0; ct < 8; ++ct) { float v = acc[rt][ct][rr]; s += v; s2 += v * v; }
      s  += __shfl_xor(s, 1);  s2 += __shfl_xor(s2, 1);
      s  += __shfl_xor(s, 2);  s2 += __shfl_xor(s2, 2);
      s  += __shfl_xor(s, 4);  s2 += __shfl_xor(s2, 4);
      s  += __shfl_xor(s, 8);  s2 += __shfl_xor(s2, 8);
      float m = s * (1.f / 128.f);
      float var = fmaxf(s2 * (1.f / 128.f) - m * m, 0.f);
      mu[rt][rr] = m; rs[rt][rr] = rsqrtf(var + 1e-5f);
    }

  float gv[8], bev[8];
#pragma unroll
  for (int ct = 0; ct < 8; ++ct) {
    gv[ct]  = a.g[ct * 16 + l15];
    bev[ct] = a.beta[ct * 16 + l15];
  }

  // ---- epilogue (guarded rows; scalar form) ----
#pragma unroll
  for (int rt = 0; rt < RT; ++rt)
#pragma unroll
    for (int rr = 0; rr < 4; ++rr) {
      const int row = rbase + rt * 16 + quad * 4 + rr;
      if (row >= M) continue;
      if constexpr (MODE == 2) {
#pragma unroll
        for (int ct = 0; ct < 8; ++ct) {
          const int col = ct * 16 + l15;
          float y = (acc[rt][ct][rr] - mu[rt][rr]) * rs[rt][rr] * gv[ct] + bev[ct];
          a.edge_lat[(size_t)row * LDIM + col] += y;                 // residual
          a.new_e[(size_t)row * LDIM + col] = (__bf16)y;             // for agg
        }
      } else if constexpr (MODE == 3) {
#pragma unroll
        for (int ct = 0; ct < 8; ++ct) {
          const int col = ct * 16 + l15;
          float y = (acc[rt][ct][rr] - mu[rt][rr]) * rs[rt][rr] * gv[ct] + bev[ct];
          float nv = a.node_lat[(size_t)row * LDIM + col] + y;       // residual
          a.node_lat[(size_t)row * LDIM + col] = nv;
          a.node_bf[(size_t)row * LDIM + col] = (__bf16)nv;          // mirror
        }
      } else if constexpr (MODE == 0) {
#pragma unroll
        for (int ct = 0; ct < 8; ++ct) {
          const int col = ct * 16 + l15;
          float y = (acc[rt][ct][rr] - mu[rt][rr]) * rs[rt][rr] * gv[ct] + bev[ct];
          a.node_lat[(size_t)row * LDIM + col] = y;
          a.node_bf[(size_t)row * LDIM + col] = (__bf16)y;           // mirror
        }
      } else {
#pragma unroll
        for (int ct = 0; ct < 8; ++ct) {
          const int col = ct * 16 + l15;
          float y = (acc[rt][ct][rr] - mu[rt][rr]) * rs[rt][rr] * gv[ct] + bev[ct];
          a.edge_lat[(size_t)row * LDIM + col] = y;
        }
      }
    }
}

// ---------------------------------------------------------------------------
// Decoder: h = swish(node_lat @ W1 + b1); dec = h @ W2 + b2; out[t,n] = dec*dt
// Processes 64 nodes per block -> needs its own grid size (DEC_BLOCKS).
// ---------------------------------------------------------------------------
__global__ __launch_bounds__(256) void decode_kernel(
    const float* __restrict__ node_lat,
    const float* __restrict__ W1, const float* __restrict__ b1,
    const float* __restrict__ W2, const float* __restrict__ b2,
    float* __restrict__ out) {
  __shared__ float X[64][129];
  const int n0 = blockIdx.x * 64;
  for (int idx = threadIdx.x; idx < 64 * 32; idx += 256) {
    int r = idx >> 5, c4 = idx & 31;
    int n = n0 + r; if (n >= N_NODES) n = N_NODES - 1;
    float4 v = *((const float4*)(node_lat + (size_t)n * 128) + c4);
    X[r][c4 * 4 + 0] = v.x; X[r][c4 * 4 + 1] = v.y;
    X[r][c4 * 4 + 2] = v.z; X[r][c4 * 4 + 3] = v.w;
  }
  __syncthreads();
  const int r = threadIdx.x;
  if (r < 64) {
    const int n = n0 + r;
    if (n < N_NODES) {
      float h[8];
#pragma unroll
      for (int j = 0; j < 8; ++j) h[j] = b1[j];
      for (int k = 0; k < 128; ++k) {
        float xv = X[r][k];
#pragma unroll
        for (int j = 0; j < 8; ++j) h[j] = fmaf(xv, W1[k * 8 + j], h[j]);
      }
#pragma unroll
      for (int j = 0; j < 8; ++j) h[j] = h[j] / (1.f + expf(-h[j]));  // swish
#pragma unroll
      for (int t = 0; t < 5; ++t) {
        float d = b2[t];
#pragma unroll
        for (int j = 0; j < 8; ++j) d = fmaf(h[j], W2[j * 5 + t], d);
        out[t * N_NODES + n] = d * (float)(t + 1);
      }
    }
  }
}

// ---------------------------------------------------------------------------
extern "C" void kernel_launch(void* const* d_in, const int* in_sizes, int n_in,
                              void* d_out, int out_size, void* d_ws, size_t ws_size,
                              hipStream_t stream) {
  (void)in_sizes; (void)n_in; (void)out_size; (void)ws_size;

  const float* node_features = (const float*)d_in[0];
  const float* edge_features = (const float*)d_in[1];
  const int*   senders       = (const int*)d_in[2];
  const int*   receivers     = (const int*)d_in[3];
  const float* node_mean = (const float*)d_in[4];
  const float* node_std  = (const float*)d_in[5];
  const float* edge_mean = (const float*)d_in[6];
  const float* edge_std  = (const float*)d_in[7];
  const float* enc_n_W1 = (const float*)d_in[8];
  const float* enc_n_b1 = (const float*)d_in[9];
  const float* enc_n_W2 = (const float*)d_in[10];
  const float* enc_n_b2 = (const float*)d_in[11];
  const float* enc_n_g    = (const float*)d_in[12];
  const float* enc_n_beta = (const float*)d_in[13];
  const float* enc_e_W1 = (const float*)d_in[14];
  const float* enc_e_b1 = (const float*)d_in[15];
  const float* enc_e_W2 = (const float*)d_in[16];
  const float* enc_e_b2 = (const float*)d_in[17];
  const float* enc_e_g    = (const float*)d_in[18];
  const float* enc_e_beta = (const float*)d_in[19];
  const float* blk_e_W1 = (const float*)d_in[20];
  const float* blk_e_b1 = (const float*)d_in[21];
  const float* blk_e_W2 = (const float*)d_in[22];
  const float* blk_e_b2 = (const float*)d_in[23];
  const float* blk_e_g    = (const float*)d_in[24];
  const float* blk_e_beta = (const float*)d_in[25];
  const float* blk_n_W1 = (const float*)d_in[26];
  const float* blk_n_b1 = (const float*)d_in[27];
  const float* blk_n_W2 = (const float*)d_in[28];
  const float* blk_n_b2 = (const float*)d_in[29];
  const float* blk_n_g    = (const float*)d_in[30];
  const float* blk_n_beta = (const float*)d_in[31];
  const float* dec_W1 = (const float*)d_in[32];
  const float* dec_b1 = (const float*)d_in[33];
  const float* dec_W2 = (const float*)d_in[34];
  const float* dec_b2 = (const float*)d_in[35];

  // ---- workspace layout (bytes, all 16B-aligned) ----
  char* ws = (char*)d_ws;
  float*  node_lat = (float*)(ws);                   // 10,240,000
  float*  edge_lat = (float*)(ws + 10240000);        // 51,200,000
  __bf16* new_e    = (__bf16*)(ws + 61440000);       // 25,600,000 (bf16 E x 128)
  __bf16* wb       = (__bf16*)(ws + 87040000);       // 1,458,176 (bf16 weights)
  int* counts    = (int*)(ws + 88498176);            // 80,000
  int* row_ptr   = (int*)(ws + 88578176);            // 80,004
  int* cursor    = (int*)(ws + 88658192);            // 80,000
  int* edge_list = (int*)(ws + 88738192);            // 400,000
  __bf16* aggr_bf = (__bf16*)(ws + 89138192);        // 5,120,000
  __bf16* node_bf = (__bf16*)(ws + 94258192);        // 5,120,000 -> ends 99,378,192

  __bf16* enW1s = wb;                    // 128*32
  __bf16* enW2s = enW1s + 4096;          // 128*128
  __bf16* eeW1s = enW2s + 16384;         // 128*32
  __bf16* eeW2s = eeW1s + 4096;          // 128*128
  __bf16* beW1s = eeW2s + 16384;         // 6*128*384
  __bf16* beW2s = beW1s + 6 * 49152;     // 6*128*128
  __bf16* bnW1s = beW2s + 6 * 16384;     // 6*128*256
  __bf16* bnW2s = bnW1s + 6 * 32768;     // 6*128*128

  // ---- prep: weight frag-major swizzle + zero CSR counts ----
  PrepArgs pa;
  pa.s_enW1 = enc_n_W1; pa.s_enW2 = enc_n_W2; pa.s_eeW1 = enc_e_W1; pa.s_eeW2 = enc_e_W2;
  pa.s_beW1 = blk_e_W1; pa.s_beW2 = blk_e_W2; pa.s_bnW1 = blk_n_W1; pa.s_bnW2 = blk_n_W2;
  pa.d_enW1 = enW1s; pa.d_enW2 = enW2s; pa.d_eeW1 = eeW1s; pa.d_eeW2 = eeW2s;
  pa.d_beW1 = beW1s; pa.d_beW2 = beW2s; pa.d_bnW1 = bnW1s; pa.d_bnW2 = bnW2s;
  pa.counts = counts;
  prep_kernel<<<2927, 256, 0, stream>>>(pa);   // 729,088 weight elems + 20,000

  // ---- CSR build ----
  hist_kernel<<<(N_EDGES + 255) / 256, 256, 0, stream>>>(receivers, counts);
  scan_kernel<<<1, 1024, 0, stream>>>(counts, row_ptr, cursor);
  fill_kernel<<<(N_EDGES + 255) / 256, 256, 0, stream>>>(receivers, cursor, edge_list);

  const int NODE_BLOCKS = (N_NODES + 31) / 32;     // 625 (mlp2: 32 rows/block, 1 wave)
  const int EDGE_BLOCKS = (N_EDGES + 31) / 32;     // 3125
  const int DEC_BLOCKS  = (N_NODES + 63) / 64;     // 313 (decode: 64 rows/block)
  const int AGG_BLOCKS  = (N_NODES + 3) / 4;       // 5000 (agg: 4 nodes/block)

  MlpArgs base;
  base.node_lat = node_lat; base.edge_lat = edge_lat; base.new_e = new_e;
  base.aggr_bf = aggr_bf; base.node_bf = node_bf;
  base.senders = senders; base.receivers = receivers;
  base.x = nullptr; base.mean = nullptr; base.stdv = nullptr;

  // ---- encoders ----
  {
    MlpArgs a = base;
    a.x = node_features; a.mean = node_mean; a.stdv = node_std;
    a.W1t = enW1s; a.W2t = enW2s;
    a.b1 = enc_n_b1; a.b2 = enc_n_b2; a.g = enc_n_g; a.beta = enc_n_beta;
    a.M = N_NODES;
    mlp2_kernel<32, 0><<<NODE_BLOCKS, 64, 0, stream>>>(a);
  }
  {
    MlpArgs a = base;
    a.x = edge_features; a.mean = edge_mean; a.stdv = edge_std;
    a.W1t = eeW1s; a.W2t = eeW2s;
    a.b1 = enc_e_b1; a.b2 = enc_e_b2; a.g = enc_e_g; a.beta = enc_e_beta;
    a.M = N_EDGES;
    mlp2_kernel<32, 1><<<EDGE_BLOCKS, 64, 0, stream>>>(a);
  }

  // ---- message-passing steps ----
  for (int i = 0; i < NSTEPS; ++i) {
    {
      MlpArgs a = base;
      a.W1t = beW1s + (size_t)i * 49152; a.W2t = beW2s + (size_t)i * 16384;
      a.b1 = blk_e_b1 + i * 128; a.b2 = blk_e_b2 + i * 128;
      a.g = blk_e_g + i * 128; a.beta = blk_e_beta + i * 128;
      a.M = N_EDGES;
      mlp2_kernel<384, 2><<<EDGE_BLOCKS, 64, 0, stream>>>(a);
    }
    agg_kernel<<<AGG_BLOCKS, 256, 0, stream>>>(row_ptr, edge_list, new_e, aggr_bf);
    {
      MlpArgs a = base;
      a.W1t = bnW1s + (size_t)i * 32768; a.W2t = bnW2s + (size_t)i * 16384;
      a.b1 = blk_n_b1 + i * 128; a.b2 = blk_n_b2 + i * 128;
      a.g = blk_n_g + i * 128; a.beta = blk_n_beta + i * 128;
      a.M = N_NODES;
      mlp2_kernel<256, 3><<<NODE_BLOCKS, 64, 0, stream>>>(a);
    }
  }

  // ---- decoder ----
  decode_kernel<<<DEC_BLOCKS, 256, 0, stream>>>(
      node_lat, dec_W1, dec_b1, dec_W2, dec_b2, (float*)d_out);
}